// Round 4
// baseline (169.733 us; speedup 1.0000x reference)
//
#include <hip/hip_runtime.h>
#include <hip/hip_bf16.h>

// Problem constants
#define B_      4
#define C_IN    64
#define H_      64
#define W_      64
#define OUT_CH  128
#define HP_     66          // padded height/width (halo = features(0))
#define CF      576         // K per tap: 9 features * 64 channels, cf = j*64 + c
#define WP_BYTES  (9 * OUT_CH * CF * 2)          // 1,327,104
#define F_BYTES   (B_ * HP_ * HP_ * CF * 2)      // 20,072,448
#define P_OFFSET  (WP_BYTES + F_BYTES)           // 21,399,552 (16B aligned)
#define NSPLIT  6
// partials: 6 groups x 524288 half4 x 8 B = 25,165,824 B  (ws end ~46.6 MB)

typedef __bf16 bf16x8 __attribute__((ext_vector_type(8)));
typedef float  f32x4  __attribute__((ext_vector_type(4)));
typedef _Float16 half4 __attribute__((ext_vector_type(4)));

// silu + cubic B-spline bases (Cox-de Boor) — identical semantics to r1-r3 (passed).
__device__ __forceinline__ void compute_features(float x, float f[9]) {
    f[0] = x / (1.0f + __expf(-x));
    float g[12];
#pragma unroll
    for (int i = 0; i < 12; ++i) g[i] = (float)(i - 3) * 0.4f - 1.0f;
    float bb[11];
#pragma unroll
    for (int i = 0; i < 11; ++i) bb[i] = (x >= g[i] && x < g[i + 1]) ? 1.0f : 0.0f;
#pragma unroll
    for (int i = 0; i < 10; ++i)
        bb[i] = (x - g[i]) * (1.0f / (g[i + 1] - g[i])) * bb[i]
              + (g[i + 2] - x) * (1.0f / (g[i + 2] - g[i + 1])) * bb[i + 1];
#pragma unroll
    for (int i = 0; i < 9; ++i)
        bb[i] = (x - g[i]) * (1.0f / (g[i + 2] - g[i])) * bb[i]
              + (g[i + 3] - x) * (1.0f / (g[i + 3] - g[i + 1])) * bb[i + 1];
#pragma unroll
    for (int i = 0; i < 8; ++i)
        bb[i] = (x - g[i]) * (1.0f / (g[i + 3] - g[i])) * bb[i]
              + (g[i + 4] - x) * (1.0f / (g[i + 4] - g[i + 1])) * bb[i + 1];
#pragma unroll
    for (int i = 0; i < 8; ++i) f[1 + i] = bb[i];
}

// Kernel 1: pack merged weights -> bf16, Wp[(tap*128 + o)*576 + j*64 + c]
__global__ __launch_bounds__(256) void pack_kernel(
        const float* __restrict__ bw, const float* __restrict__ sw,
        const float* __restrict__ sc, __hip_bfloat16* __restrict__ Wp) {
    int idx = blockIdx.x * 256 + threadIdx.x;          // 0 .. 663551
    if (idx < 589824) {                                 // spline: idx = o*4608 + d*8 + j
        int o = idx / 4608;
        int r = idx - o * 4608;
        int d = r >> 3;
        int j = r & 7;
        int tap = d % 9;
        int c   = d / 9;
        float v = sw[idx] * sc[o * 576 + d];
        Wp[(tap * OUT_CH + o) * CF + (j + 1) * 64 + c] = __float2bfloat16(v);
    } else {                                            // base: k = o*576 + d
        int k = idx - 589824;
        int o = k / 576;
        int d = k - o * 576;
        int tap = d % 9;
        int c   = d / 9;
        Wp[(tap * OUT_CH + o) * CF + c] = __float2bfloat16(bw[k]);
    }
}

// Kernel 2: per-pixel features with halo. F[((b*66+hp)*66+wp)*576 + j*64 + c]
__global__ __launch_bounds__(256) void feat_kernel(
        const float* __restrict__ x, __hip_bfloat16* __restrict__ F) {
    __shared__ float xs[64][65];
    int b  = blockIdx.x / HP_;
    int hp = blockIdx.x % HP_;
    int h  = hp - 1;
    int tid = threadIdx.x;

    float f0[9];
    compute_features(0.0f, f0);

    bool interior_row = (h >= 0) && (h < H_);
    if (interior_row) {
        int wl  = tid & 63;
        int c16 = tid >> 6;
#pragma unroll
        for (int i = 0; i < 16; ++i) {
            int c = c16 * 16 + i;
            xs[c][wl] = x[((b * C_IN + c) * H_ + h) * W_ + wl];
        }
    }
    __syncthreads();

    int c  = tid & 63;
    int wg = tid >> 6;
    __hip_bfloat16* Frow = F + (size_t)((b * HP_ + hp) * HP_) * CF;

    if (!interior_row) {
        for (int wp = wg; wp < HP_; wp += 4) {
            __hip_bfloat16* dst = Frow + (size_t)wp * CF + c;
#pragma unroll
            for (int j = 0; j < 9; ++j) dst[j * 64] = __float2bfloat16(f0[j]);
        }
        return;
    }
    if (wg == 0) {
        __hip_bfloat16* dst = Frow + c;
#pragma unroll
        for (int j = 0; j < 9; ++j) dst[j * 64] = __float2bfloat16(f0[j]);
    }
    if (wg == 3) {
        __hip_bfloat16* dst = Frow + (size_t)65 * CF + c;
#pragma unroll
        for (int j = 0; j < 9; ++j) dst[j * 64] = __float2bfloat16(f0[j]);
    }
    for (int w2 = wg; w2 < 64; w2 += 4) {
        float xv = xs[c][w2];
        float f[9];
        compute_features(xv, f);
        __hip_bfloat16* dst = Frow + (size_t)(w2 + 1) * CF + c;
#pragma unroll
        for (int j = 0; j < 9; ++j) dst[j * 64] = __float2bfloat16(f[j]);
    }
}

// Kernel 3: zero-LDS zero-barrier implicit-GEMM. Grid = 768 = 6 k-groups x 128
// pixel tiles -> exactly 3 blocks/CU, ALL blocks co-resident (no tail).
// Block: 128 o x 128 pix (2 output rows); 4 waves 2x2, wave = 64 o x one 64-pix
// image row, 4x4 tiles of 16x16x32 bf16. Both operands loaded straight from
// global into frags: weights hit L2 (1.3 MB resident), features hit L3 (20 MB
// resident); L1 dedups the 2x intra-block wave overlap. Compiler pipelines the
// 16 loads/unit across the MFMA stream with fine-grained vmcnt — no s_barrier
// anywhere in the K-loop. K split into 81 units of 64 (u = tap*9 + kc),
// group g owns 13 or 14 units. Partials to fp16 in a permuted fully-coalesced
// layout (each store inst = 512 B contiguous).
__global__ __launch_bounds__(256, 3) void gemm_kernel(
        const __hip_bfloat16* __restrict__ Fb, const __hip_bfloat16* __restrict__ Wpb,
        half4* __restrict__ P) {
    const ushort* F  = (const ushort*)Fb;
    const ushort* Wp = (const ushort*)Wpb;

    int tid  = threadIdx.x;
    int lane = tid & 63;
    int w    = tid >> 6;
    int l15  = lane & 15;
    int lq   = lane >> 4;
    int wm   = w & 1;                // out_ch half
    int wn   = w >> 1;               // which of the 2 image rows

    int blk = blockIdx.x;
    int g   = blk >> 7;              // k-group 0..5
    int t   = blk & 127;
    int b   = t >> 5;
    int ho0 = (t & 31) << 1;
    int u0  = (g < 3) ? g * 13 : 39 + (g - 3) * 14;
    int nu  = (g < 3) ? 13 : 14;

    f32x4 acc[4][4];
#pragma unroll
    for (int i = 0; i < 4; ++i)
#pragma unroll
        for (int j = 0; j < 4; ++j) acc[i][j] = (f32x4){0.f, 0.f, 0.f, 0.f};

    // lane-invariant base pointers (element arithmetic; rows are 576 elems)
    const ushort* Wl = Wp + (size_t)(wm * 64 + l15) * CF + lq * 8;
    const ushort* Fl = F + (size_t)((b * HP_ + ho0 + wn) * HP_ + l15) * CF + lq * 8;

    for (int ui = 0; ui < nu; ++ui) {
        int u   = u0 + ui;
        int tap = u / 9;
        int kc  = u - tap * 9;
        int kh  = tap / 3;
        int kw  = tap - kh * 3;
        int koff = kc * 64;
        const ushort* wbase = Wl + (size_t)(tap * OUT_CH) * CF + koff;
        const ushort* fbase = Fl + (size_t)(kh * HP_ + kw) * CF + koff;

        bf16x8 af[4][2], bf[4][2];
#pragma unroll
        for (int ks = 0; ks < 2; ++ks)
#pragma unroll
            for (int mt = 0; mt < 4; ++mt)
                af[mt][ks] = *(const bf16x8*)(wbase + (size_t)mt * 16 * CF + ks * 32);
#pragma unroll
        for (int ks = 0; ks < 2; ++ks)
#pragma unroll
            for (int nt = 0; nt < 4; ++nt)
                bf[nt][ks] = *(const bf16x8*)(fbase + (size_t)nt * 16 * CF + ks * 32);
#pragma unroll
        for (int ks = 0; ks < 2; ++ks)
#pragma unroll
            for (int mt = 0; mt < 4; ++mt)
#pragma unroll
                for (int nt = 0; nt < 4; ++nt)
                    acc[mt][nt] = __builtin_amdgcn_mfma_f32_16x16x32_bf16(
                        af[mt][ks], bf[nt][ks], acc[mt][nt], 0, 0, 0);
    }

    // epilogue: permuted coalesced fp16 partials.
    // P[(((blk*4 + w)*16 + mt*4+nt)*64 + lane] = half4(acc[0..3])
    half4* Pp = P + ((size_t)blk * 4 + w) * 16 * 64 + lane;
#pragma unroll
    for (int mt = 0; mt < 4; ++mt)
#pragma unroll
        for (int nt = 0; nt < 4; ++nt) {
            half4 h;
#pragma unroll
            for (int r = 0; r < 4; ++r) h[r] = (_Float16)acc[mt][nt][r];
            Pp[(mt * 4 + nt) * 64] = h;
        }
}

// Kernel 4: reduce 6 permuted fp16 partials -> fp32 out (decodes the layout).
__global__ __launch_bounds__(256) void reduce_kernel(
        const half4* __restrict__ P, float* __restrict__ out) {
    const int GS = 524288;                    // half4 per k-group (128*4*16*64)
    int i = blockIdx.x * 256 + threadIdx.x;   // 0..524287
    float s[4] = {0.f, 0.f, 0.f, 0.f};
#pragma unroll
    for (int g = 0; g < NSPLIT; ++g) {
        half4 v = P[(size_t)g * GS + i];
#pragma unroll
        for (int r = 0; r < 4; ++r) s[r] += (float)v[r];
    }
    int lane = i & 63;
    int frag = (i >> 6) & 15;
    int w    = (i >> 10) & 3;
    int t    = i >> 12;
    int l15 = lane & 15, lq = lane >> 4;
    int mt = frag >> 2, nt = frag & 3;
    int wm = w & 1, wn = w >> 1;
    int b  = t >> 5;
    int ho = ((t & 31) << 1) + wn;
    int o  = wm * 64 + mt * 16 + lq * 4;
    int wo = nt * 16 + l15;
    float* dst = out + ((size_t)(b * OUT_CH + o) << 12) + (ho << 6) + wo;
#pragma unroll
    for (int r = 0; r < 4; ++r)
        dst[(size_t)r << 12] = s[r];
}

extern "C" void kernel_launch(void* const* d_in, const int* in_sizes, int n_in,
                              void* d_out, int out_size, void* d_ws, size_t ws_size,
                              hipStream_t stream) {
    const float* x  = (const float*)d_in[0];   // (4,64,64,64)
    const float* bw = (const float*)d_in[1];   // (128,576)
    const float* sw = (const float*)d_in[2];   // (128,576,8)
    const float* sc = (const float*)d_in[3];   // (128,576)
    float* out = (float*)d_out;                // (4,128,64,64) fp32

    __hip_bfloat16* Wp = (__hip_bfloat16*)d_ws;
    __hip_bfloat16* F  = (__hip_bfloat16*)((char*)d_ws + WP_BYTES);
    half4*          P  = (half4*)((char*)d_ws + P_OFFSET);

    pack_kernel<<<2592, 256, 0, stream>>>(bw, sw, sc, Wp);
    feat_kernel<<<B_ * HP_, 256, 0, stream>>>(x, F);
    gemm_kernel<<<768, 256, 0, stream>>>(F, Wp, P);
    reduce_kernel<<<2048, 256, 0, stream>>>(P, out);
}

// Round 5
// 151.568 us; speedup vs baseline: 1.1199x; 1.1199x over previous
//
#include <hip/hip_runtime.h>
#include <hip/hip_bf16.h>

// Problem constants
#define B_      4
#define C_IN    64
#define H_      64
#define W_      64
#define OUT_CH  128
#define HP_     66          // padded height/width (halo = features(0))
#define CF      576         // K per tap: 9 features * 64 channels, cf = j*64 + c
#define WP_BYTES  (9 * OUT_CH * CF * 2)          // 1,327,104
#define F_BYTES   (B_ * HP_ * HP_ * CF * 2)      // 20,072,448
#define P_OFFSET  (WP_BYTES + F_BYTES)           // 21,399,552 (16B aligned)
#define NSPLIT  9
// partials: 9 groups x 524288 half4 x 8 B = 37,748,736 B (ws end ~59.1 MB)

typedef __bf16 bf16x8 __attribute__((ext_vector_type(8)));
typedef float  f32x4  __attribute__((ext_vector_type(4)));
typedef _Float16 half4 __attribute__((ext_vector_type(4)));

// silu + cubic B-spline bases (Cox-de Boor) — identical semantics to r1-r4 (passed).
__device__ __forceinline__ void compute_features(float x, float f[9]) {
    f[0] = x / (1.0f + __expf(-x));
    float g[12];
#pragma unroll
    for (int i = 0; i < 12; ++i) g[i] = (float)(i - 3) * 0.4f - 1.0f;
    float bb[11];
#pragma unroll
    for (int i = 0; i < 11; ++i) bb[i] = (x >= g[i] && x < g[i + 1]) ? 1.0f : 0.0f;
#pragma unroll
    for (int i = 0; i < 10; ++i)
        bb[i] = (x - g[i]) * (1.0f / (g[i + 1] - g[i])) * bb[i]
              + (g[i + 2] - x) * (1.0f / (g[i + 2] - g[i + 1])) * bb[i + 1];
#pragma unroll
    for (int i = 0; i < 9; ++i)
        bb[i] = (x - g[i]) * (1.0f / (g[i + 2] - g[i])) * bb[i]
              + (g[i + 3] - x) * (1.0f / (g[i + 3] - g[i + 1])) * bb[i + 1];
#pragma unroll
    for (int i = 0; i < 8; ++i)
        bb[i] = (x - g[i]) * (1.0f / (g[i + 3] - g[i])) * bb[i]
              + (g[i + 4] - x) * (1.0f / (g[i + 4] - g[i + 1])) * bb[i + 1];
#pragma unroll
    for (int i = 0; i < 8; ++i) f[1 + i] = bb[i];
}

// Kernel 1: pack merged weights -> bf16, Wp[(tap*128 + o)*576 + j*64 + c]
__global__ __launch_bounds__(256) void pack_kernel(
        const float* __restrict__ bw, const float* __restrict__ sw,
        const float* __restrict__ sc, __hip_bfloat16* __restrict__ Wp) {
    int idx = blockIdx.x * 256 + threadIdx.x;          // 0 .. 663551
    if (idx < 589824) {                                 // spline: idx = o*4608 + d*8 + j
        int o = idx / 4608;
        int r = idx - o * 4608;
        int d = r >> 3;
        int j = r & 7;
        int tap = d % 9;
        int c   = d / 9;
        float v = sw[idx] * sc[o * 576 + d];
        Wp[(tap * OUT_CH + o) * CF + (j + 1) * 64 + c] = __float2bfloat16(v);
    } else {                                            // base: k = o*576 + d
        int k = idx - 589824;
        int o = k / 576;
        int d = k - o * 576;
        int tap = d % 9;
        int c   = d / 9;
        Wp[(tap * OUT_CH + o) * CF + c] = __float2bfloat16(bw[k]);
    }
}

// Kernel 2: per-pixel features with halo. F[((b*66+hp)*66+wp)*576 + j*64 + c]
__global__ __launch_bounds__(256) void feat_kernel(
        const float* __restrict__ x, __hip_bfloat16* __restrict__ F) {
    __shared__ float xs[64][65];
    int b  = blockIdx.x / HP_;
    int hp = blockIdx.x % HP_;
    int h  = hp - 1;
    int tid = threadIdx.x;

    float f0[9];
    compute_features(0.0f, f0);

    bool interior_row = (h >= 0) && (h < H_);
    if (interior_row) {
        int wl  = tid & 63;
        int c16 = tid >> 6;
#pragma unroll
        for (int i = 0; i < 16; ++i) {
            int c = c16 * 16 + i;
            xs[c][wl] = x[((b * C_IN + c) * H_ + h) * W_ + wl];
        }
    }
    __syncthreads();

    int c  = tid & 63;
    int wg = tid >> 6;
    __hip_bfloat16* Frow = F + (size_t)((b * HP_ + hp) * HP_) * CF;

    if (!interior_row) {
        for (int wp = wg; wp < HP_; wp += 4) {
            __hip_bfloat16* dst = Frow + (size_t)wp * CF + c;
#pragma unroll
            for (int j = 0; j < 9; ++j) dst[j * 64] = __float2bfloat16(f0[j]);
        }
        return;
    }
    if (wg == 0) {
        __hip_bfloat16* dst = Frow + c;
#pragma unroll
        for (int j = 0; j < 9; ++j) dst[j * 64] = __float2bfloat16(f0[j]);
    }
    if (wg == 3) {
        __hip_bfloat16* dst = Frow + (size_t)65 * CF + c;
#pragma unroll
        for (int j = 0; j < 9; ++j) dst[j * 64] = __float2bfloat16(f0[j]);
    }
    for (int w2 = wg; w2 < 64; w2 += 4) {
        float xv = xs[c][w2];
        float f[9];
        compute_features(xv, f);
        __hip_bfloat16* dst = Frow + (size_t)(w2 + 1) * CF + c;
#pragma unroll
        for (int j = 0; j < 9; ++j) dst[j * 64] = __float2bfloat16(f[j]);
    }
}

// Kernel 3: footprint-shared implicit-GEMM, ONE barrier per block.
// Grid 1152 = 9 j-groups x 128 pixel tiles (2 output rows). Block = 128 threads
// = 2 waves; wave = 64 o x 128 px, 4 mt x 8 nt of 16x16x32 bf16 (128-AGPR acc).
// Footprint: 4 padded rows x 66 wp x 64 k (j-slice) staged ONCE into LDS via
// global_load_lds dwordx4 with granule-XOR swizzle (slot = q*8 + (c8 ^ (q&7)),
// q = row*68+wp) -> staging is lane-contiguous, frag reads 2-way (free).
// All 9 taps read shifted LDS windows => A global traffic 40 MB (vs 170 MB).
// Weights (L2-resident) are loaded per-wave straight into A-frags — no barrier.
__global__ __launch_bounds__(128, 2) void gemm_kernel(
        const __hip_bfloat16* __restrict__ Fb, const __hip_bfloat16* __restrict__ Wpb,
        half4* __restrict__ P) {
    __shared__ __align__(16) ushort Fs[272 * 8 * 8];   // 272 q x 8 granules x 16 B = 34,816 B

    const ushort* F  = (const ushort*)Fb;
    const ushort* Wp = (const ushort*)Wpb;

    int tid  = threadIdx.x;
    int lane = tid & 63;
    int w    = tid >> 6;             // 0..1 = out_ch half
    int l15  = lane & 15;
    int lq   = lane >> 4;

    int blk = blockIdx.x;
    int g   = blk >> 7;              // j-group 0..8
    int t   = blk & 127;             // pixel tile
    int b   = t >> 5;
    int ho0 = (t & 31) << 1;         // 2 output rows; footprint rows ho0..ho0+3

    // ---- stage footprint (one shot): 2176 granules, 17 rounds of 128 ----
    const ushort* Fbase = F + (size_t)((b * HP_ + ho0) * HP_) * CF + g * 64;
#pragma unroll
    for (int i = 0; i < 17; ++i) {
        int idx = i * 128 + tid;     // 0..2175
        int q   = idx >> 3;          // row*68 + wp, 0..271
        int row = q / 68;
        int wp  = q - row * 68;
        if (wp > 65) wp = 65;        // pad cols: harmless dup
        int c8  = (idx & 7) ^ (q & 7);
        const ushort* src = Fbase + ((size_t)row * HP_ + wp) * CF + c8 * 8;
        __builtin_amdgcn_global_load_lds(
            (const __attribute__((address_space(1))) unsigned int*)src,
            (__attribute__((address_space(3))) unsigned int*)&Fs[idx * 8],
            16, 0, 0);
    }

    f32x4 acc[4][8];
#pragma unroll
    for (int i = 0; i < 4; ++i)
#pragma unroll
        for (int j = 0; j < 8; ++j) acc[i][j] = (f32x4){0.f, 0.f, 0.f, 0.f};

    __syncthreads();                 // the ONLY barrier

    // weight frag base: o = w*64 + mt*16 + l15, k = g*64 + ks*32 + lq*8
    const ushort* Wl = Wp + (size_t)(w * 64 + l15) * CF + g * 64 + lq * 8;

#pragma unroll
    for (int tap = 0; tap < 9; ++tap) {
        const int kh = tap / 3;
        const int kw = tap - kh * 3;
#pragma unroll
        for (int ks = 0; ks < 2; ++ks) {
            bf16x8 wf[4];
#pragma unroll
            for (int mt = 0; mt < 4; ++mt)
                wf[mt] = *(const bf16x8*)(Wl + (size_t)(tap * OUT_CH + mt * 16) * CF + ks * 32);
            bf16x8 af[8];
#pragma unroll
            for (int nt = 0; nt < 8; ++nt) {
                int row  = (nt >> 2) + kh;                 // 0..3
                int wp   = (nt & 3) * 16 + l15 + kw;       // 0..65
                int q    = row * 68 + wp;
                int c8   = (ks * 4 + lq) ^ (q & 7);
                af[nt] = *(const bf16x8*)&Fs[(q * 8 + c8) * 8];
            }
#pragma unroll
            for (int mt = 0; mt < 4; ++mt)
#pragma unroll
                for (int nt = 0; nt < 8; ++nt)
                    acc[mt][nt] = __builtin_amdgcn_mfma_f32_16x16x32_bf16(
                        wf[mt], af[nt], acc[mt][nt], 0, 0, 0);
        }
    }

    // epilogue: coalesced fp16 partials, 512 B per store-row.
    // P[blk*4096 + (w*32 + mt*8 + nt)*64 + lane]
    half4* Pp = P + (size_t)blk * 4096 + (size_t)w * 2048 + lane;
#pragma unroll
    for (int mt = 0; mt < 4; ++mt)
#pragma unroll
        for (int nt = 0; nt < 8; ++nt) {
            half4 h;
#pragma unroll
            for (int r = 0; r < 4; ++r) h[r] = (_Float16)acc[mt][nt][r];
            Pp[(mt * 8 + nt) * 64] = h;
        }
}

// Kernel 4: reduce 9 permuted fp16 partials -> fp32 out (decodes the layout).
__global__ __launch_bounds__(256) void reduce_kernel(
        const half4* __restrict__ P, float* __restrict__ out) {
    const int GS = 524288;                    // half4 per j-group (128 tiles * 4096)
    int i = blockIdx.x * 256 + threadIdx.x;   // 0..524287
    float s[4] = {0.f, 0.f, 0.f, 0.f};
#pragma unroll
    for (int g = 0; g < NSPLIT; ++g) {
        half4 v = P[(size_t)g * GS + i];
#pragma unroll
        for (int r = 0; r < 4; ++r) s[r] += (float)v[r];
    }
    int lane = i & 63;
    int fr   = (i >> 6) & 31;
    int w    = (i >> 11) & 1;
    int t    = i >> 12;                       // 0..127
    int l15 = lane & 15, lq = lane >> 4;
    int mt = fr >> 3, nt = fr & 7;
    int o  = w * 64 + mt * 16 + lq * 4;
    int pp = nt * 16 + l15;                   // 0..127
    int b  = t >> 5;
    int ho = ((t & 31) << 1) + (pp >> 6);
    int wo = pp & 63;
    float* dst = out + ((size_t)(b * OUT_CH + o) << 12) + (ho << 6) + wo;
#pragma unroll
    for (int r = 0; r < 4; ++r)
        dst[(size_t)r << 12] = s[r];
}

extern "C" void kernel_launch(void* const* d_in, const int* in_sizes, int n_in,
                              void* d_out, int out_size, void* d_ws, size_t ws_size,
                              hipStream_t stream) {
    const float* x  = (const float*)d_in[0];   // (4,64,64,64)
    const float* bw = (const float*)d_in[1];   // (128,576)
    const float* sw = (const float*)d_in[2];   // (128,576,8)
    const float* sc = (const float*)d_in[3];   // (128,576)
    float* out = (float*)d_out;                // (4,128,64,64) fp32

    __hip_bfloat16* Wp = (__hip_bfloat16*)d_ws;
    __hip_bfloat16* F  = (__hip_bfloat16*)((char*)d_ws + WP_BYTES);
    half4*          P  = (half4*)((char*)d_ws + P_OFFSET);

    pack_kernel<<<2592, 256, 0, stream>>>(bw, sw, sc, Wp);
    feat_kernel<<<B_ * HP_, 256, 0, stream>>>(x, F);
    gemm_kernel<<<1152, 128, 0, stream>>>(F, Wp, P);
    reduce_kernel<<<2048, 256, 0, stream>>>(P, out);
}

// Round 6
// 119.893 us; speedup vs baseline: 1.4157x; 1.2642x over previous
//
#include <hip/hip_runtime.h>
#include <hip/hip_bf16.h>

// Problem constants
#define B_      4
#define C_IN    64
#define H_      64
#define W_      64
#define OUT_CH  128
#define HP_     66          // padded height/width (halo = features(0))
#define CF      576         // K per tap: 9 features * 64 channels, cf = j*64 + c
#define WP_BYTES  (9 * OUT_CH * CF * 2)          // 1,327,104
#define F_BYTES   (B_ * HP_ * HP_ * CF * 2)      // 20,072,448
#define P_OFFSET  (WP_BYTES + F_BYTES)           // 21,399,552 (16B aligned)
// partials: 4 K-groups x (4 b x 128 o x 4096 pix) fp16 = 16,777,216 B

typedef __bf16 bf16x8 __attribute__((ext_vector_type(8)));
typedef float  f32x4  __attribute__((ext_vector_type(4)));
typedef _Float16 half8 __attribute__((ext_vector_type(8)));

// silu + cubic B-spline bases (Cox-de Boor) — identical semantics to r1-r5 (passed).
__device__ __forceinline__ void compute_features(float x, float f[9]) {
    f[0] = x / (1.0f + __expf(-x));
    float g[12];
#pragma unroll
    for (int i = 0; i < 12; ++i) g[i] = (float)(i - 3) * 0.4f - 1.0f;
    float bb[11];
#pragma unroll
    for (int i = 0; i < 11; ++i) bb[i] = (x >= g[i] && x < g[i + 1]) ? 1.0f : 0.0f;
#pragma unroll
    for (int i = 0; i < 10; ++i)
        bb[i] = (x - g[i]) * (1.0f / (g[i + 1] - g[i])) * bb[i]
              + (g[i + 2] - x) * (1.0f / (g[i + 2] - g[i + 1])) * bb[i + 1];
#pragma unroll
    for (int i = 0; i < 9; ++i)
        bb[i] = (x - g[i]) * (1.0f / (g[i + 2] - g[i])) * bb[i]
              + (g[i + 3] - x) * (1.0f / (g[i + 3] - g[i + 1])) * bb[i + 1];
#pragma unroll
    for (int i = 0; i < 8; ++i)
        bb[i] = (x - g[i]) * (1.0f / (g[i + 3] - g[i])) * bb[i]
              + (g[i + 4] - x) * (1.0f / (g[i + 4] - g[i + 1])) * bb[i + 1];
#pragma unroll
    for (int i = 0; i < 8; ++i) f[1 + i] = bb[i];
}

// Kernel 1: pack merged weights -> bf16, Wp[(tap*128 + o)*576 + j*64 + c].
__global__ __launch_bounds__(256) void pack_kernel(
        const float* __restrict__ bw, const float* __restrict__ sw,
        const float* __restrict__ sc, __hip_bfloat16* __restrict__ Wp) {
    int idx = blockIdx.x * 256 + threadIdx.x;          // 0 .. 663551
    if (idx < 589824) {                                 // spline: idx = o*4608 + d*8 + j
        int o = idx / 4608;
        int r = idx - o * 4608;
        int d = r >> 3;
        int j = r & 7;
        int tap = d % 9;
        int c   = d / 9;
        float v = sw[idx] * sc[o * 576 + d];
        Wp[(tap * OUT_CH + o) * CF + (j + 1) * 64 + c] = __float2bfloat16(v);
    } else {                                            // base: k = o*576 + d
        int k = idx - 589824;
        int o = k / 576;
        int d = k - o * 576;
        int tap = d % 9;
        int c   = d / 9;
        Wp[(tap * OUT_CH + o) * CF + c] = __float2bfloat16(bw[k]);
    }
}

// Kernel 2: per-pixel features with halo. F[((b*66+hp)*66+wp)*576 + j*64 + c]
// v3: 528 blocks (2 per row: each handles half the wp range) for ~2 blocks/CU.
__global__ __launch_bounds__(256) void feat_kernel(
        const float* __restrict__ x, __hip_bfloat16* __restrict__ F) {
    __shared__ float xs[64][65];
    int blk  = blockIdx.x;
    int half = blk & 1;
    int hp   = (blk >> 1) % HP_;
    int b    = blk / (2 * HP_);
    int h    = hp - 1;
    int tid  = threadIdx.x;

    float f0[9];
    compute_features(0.0f, f0);

    bool interior_row = (h >= 0) && (h < H_);
    if (interior_row) {
        int wl  = tid & 63;
        int c16 = tid >> 6;
#pragma unroll
        for (int i = 0; i < 16; ++i) {
            int c = c16 * 16 + i;
            xs[c][wl] = x[((b * C_IN + c) * H_ + h) * W_ + wl];
        }
    }
    __syncthreads();

    int c  = tid & 63;
    int wg = tid >> 6;
    __hip_bfloat16* Frow = F + (size_t)((b * HP_ + hp) * HP_) * CF;

    if (!interior_row) {
        int wp0 = half * 33;
        for (int wp = wp0 + wg; wp < wp0 + 33; wp += 4) {
            __hip_bfloat16* dst = Frow + (size_t)wp * CF + c;
#pragma unroll
            for (int j = 0; j < 9; ++j) dst[j * 64] = __float2bfloat16(f0[j]);
        }
        return;
    }
    if (half == 0 && wg == 0) {
        __hip_bfloat16* dst = Frow + c;                      // wp = 0
#pragma unroll
        for (int j = 0; j < 9; ++j) dst[j * 64] = __float2bfloat16(f0[j]);
    }
    if (half == 1 && wg == 3) {
        __hip_bfloat16* dst = Frow + (size_t)65 * CF + c;    // wp = 65
#pragma unroll
        for (int j = 0; j < 9; ++j) dst[j * 64] = __float2bfloat16(f0[j]);
    }
    int w2base = half * 32;
    for (int w2 = w2base + wg; w2 < w2base + 32; w2 += 4) {
        float xv = xs[c][w2];
        float f[9];
        compute_features(xv, f);
        __hip_bfloat16* dst = Frow + (size_t)(w2 + 1) * CF + c;
#pragma unroll
        for (int j = 0; j < 9; ++j) dst[j * 64] = __float2bfloat16(f[j]);
    }
}

// Kernel 3: implicit-GEMM conv, 4-way K-split — r2 structure (passed, best) with
// the __syncthreads vmcnt(0)-drain replaced by the AITER-style pipeline:
//   A (features, L3-resident): TRIPLE-buffered, prefetched 2 steps ahead
//   B (weights, L2-resident):  double-buffered, prefetched 1 step ahead
//   per step: s_waitcnt vmcnt(4) (allows only newest A-prefetch outstanding;
//   in-order FIFO retire guarantees A(i),B(i) landed) + RAW s_barrier (no fence
//   -> no drain). Issue order per step: B(i+1) x4 then A(i+2) x4.
// Grid = 512: blk = g*128 + t; block 128 o x 128 px, 4 waves 2x2, 64x64/wave.
__global__ __launch_bounds__(256, 2) void gemm_kernel(
        const __hip_bfloat16* __restrict__ Fb, const __hip_bfloat16* __restrict__ Wpb,
        _Float16* __restrict__ P) {
    __shared__ __align__(16) ushort As[3][8192];   // features, 48 KB
    __shared__ __align__(16) ushort Bs[2][8192];   // weights,  32 KB

    const ushort* F  = (const ushort*)Fb;
    const ushort* Wp = (const ushort*)Wpb;

    int tid  = threadIdx.x;
    int lane = tid & 63;
    int w    = tid >> 6;
    int l15  = lane & 15;
    int lq   = lane >> 4;
    int wm = w & 1;                  // out_ch half
    int wn = w >> 1;                 // pixel half
    int srow = lane >> 3;            // 0..7 staging sub-row
    int sl7  = lane & 7;
    int c8s  = sl7 ^ srow;           // staged c8 for this lane (swizzle-inverse)

    int blk = blockIdx.x;
    int g   = blk >> 7;              // K-group 0..3
    int t   = blk & 127;
    int b   = t >> 5;
    int ho0 = (t & 31) << 1;
    int c0 = (g == 0) ? 0 : (21 + 20 * (g - 1));   // {0,21,41,61}
    int n  = (g == 0) ? 21 : 20;                   // chunks (tap*9 + kc), 81 total

    f32x4 acc[4][4];
#pragma unroll
    for (int i = 0; i < 4; ++i)
#pragma unroll
        for (int j = 0; j < 4; ++j) acc[i][j] = (f32x4){0.f, 0.f, 0.f, 0.f};

    auto prefetchA = [&](int ch, int buf) {
        int tap = ch / 9;
        int kc  = ch - tap * 9;
        int kh  = tap / 3;
        int kw  = tap - kh * 3;
#pragma unroll
        for (int r = 0; r < 4; ++r) {
            int row = (r * 4 + w) * 8 + srow;       // pixel 0..127
            int hp = ho0 + (row >> 6) + kh;
            int wp = (row & 63) + kw;
            const ushort* srcA = F + (size_t)((b * HP_ + hp) * HP_ + wp) * CF
                                   + kc * 64 + c8s * 8;
            __builtin_amdgcn_global_load_lds(
                (const __attribute__((address_space(1))) unsigned int*)srcA,
                (__attribute__((address_space(3))) unsigned int*)&As[buf][(r * 4 + w) * 512],
                16, 0, 0);
        }
    };
    auto prefetchB = [&](int ch, int buf) {
        int tap = ch / 9;
        int kc  = ch - tap * 9;
#pragma unroll
        for (int r = 0; r < 4; ++r) {
            int row = (r * 4 + w) * 8 + srow;       // o 0..127
            const ushort* srcB = Wp + (size_t)(tap * OUT_CH + row) * CF
                                    + kc * 64 + c8s * 8;
            __builtin_amdgcn_global_load_lds(
                (const __attribute__((address_space(1))) unsigned int*)srcB,
                (__attribute__((address_space(3))) unsigned int*)&Bs[buf][(r * 4 + w) * 512],
                16, 0, 0);
        }
    };

    // prologue: B(0), A(0), A(1)  (issue order matters for vmcnt FIFO analysis)
    prefetchB(c0, 0);
    prefetchA(c0, 0);
    if (n > 1) prefetchA(c0 + 1, 1);

    for (int i = 0; i < n; ++i) {
        // Wait: need A(i), B(i) landed; newest 4 outstanding may be A(i+1).
        if (i + 1 < n) __builtin_amdgcn_s_waitcnt(0xF74);   // vmcnt(4)
        else           __builtin_amdgcn_s_waitcnt(0xF70);   // vmcnt(0) tail
        __builtin_amdgcn_s_barrier();                        // raw: no drain
        if (i + 1 < n) prefetchB(c0 + i + 1, (i + 1) & 1);
        if (i + 2 < n) prefetchA(c0 + i + 2, (i + 2) % 3);
        const ushort* Ab = As[i % 3];
        const ushort* Bb = Bs[i & 1];
#pragma unroll
        for (int ks = 0; ks < 2; ++ks) {
            bf16x8 af[4], bq[4];
#pragma unroll
            for (int mt = 0; mt < 4; ++mt) {
                int o  = wm * 64 + mt * 16 + l15;
                int sl = o * 8 + ((ks * 4 + lq) ^ (o & 7));
                af[mt] = *(const bf16x8*)&Bb[sl * 8];
            }
#pragma unroll
            for (int nt = 0; nt < 4; ++nt) {
                int p  = wn * 64 + nt * 16 + l15;
                int sl = p * 8 + ((ks * 4 + lq) ^ (p & 7));
                bq[nt] = *(const bf16x8*)&Ab[sl * 8];
            }
#pragma unroll
            for (int mt = 0; mt < 4; ++mt)
#pragma unroll
                for (int nt = 0; nt < 4; ++nt)
                    acc[mt][nt] = __builtin_amdgcn_mfma_f32_16x16x32_bf16(
                        af[mt], bq[nt], acc[mt][nt], 0, 0, 0);
        }
    }

    // epilogue: fp16 partials. P[((g*4+b)*128 + o)*4096 + ho0*64 + pix]
    _Float16* Pg = P + ((size_t)(g * 4 + b) * OUT_CH) * 4096 + ho0 * 64;
#pragma unroll
    for (int mt = 0; mt < 4; ++mt) {
        int o = wm * 64 + mt * 16 + lq * 4;
#pragma unroll
        for (int nt = 0; nt < 4; ++nt) {
            int pix = wn * 64 + nt * 16 + l15;
            _Float16* dst = Pg + (size_t)o * 4096 + pix;
#pragma unroll
            for (int r = 0; r < 4; ++r)
                dst[(size_t)r * 4096] = (_Float16)acc[mt][nt][r];
        }
    }
}

// Kernel 4: reduce 4 fp16 partials -> fp32 out. Fully coalesced half8/float4.
__global__ __launch_bounds__(256) void reduce_kernel(
        const half8* __restrict__ P, float4* __restrict__ out) {
    const int GS = 262144;                    // half8 per K-group (4*128*4096/8)
    int i = blockIdx.x * 256 + threadIdx.x;   // 0..262143
    half8 a = P[i], bb = P[GS + i], c = P[2 * GS + i], d = P[3 * GS + i];
    float4 o0, o1;
#pragma unroll
    for (int j = 0; j < 4; ++j)
        ((float*)&o0)[j] = (float)a[j] + (float)bb[j] + (float)c[j] + (float)d[j];
#pragma unroll
    for (int j = 0; j < 4; ++j)
        ((float*)&o1)[j] = (float)a[4 + j] + (float)bb[4 + j] + (float)c[4 + j] + (float)d[4 + j];
    out[i * 2]     = o0;
    out[i * 2 + 1] = o1;
}

extern "C" void kernel_launch(void* const* d_in, const int* in_sizes, int n_in,
                              void* d_out, int out_size, void* d_ws, size_t ws_size,
                              hipStream_t stream) {
    const float* x  = (const float*)d_in[0];   // (4,64,64,64)
    const float* bw = (const float*)d_in[1];   // (128,576)
    const float* sw = (const float*)d_in[2];   // (128,576,8)
    const float* sc = (const float*)d_in[3];   // (128,576)
    float* out = (float*)d_out;                // (4,128,64,64) fp32

    __hip_bfloat16* Wp = (__hip_bfloat16*)d_ws;
    __hip_bfloat16* F  = (__hip_bfloat16*)((char*)d_ws + WP_BYTES);
    _Float16*       P  = (_Float16*)((char*)d_ws + P_OFFSET);

    pack_kernel<<<2592, 256, 0, stream>>>(bw, sw, sc, Wp);
    feat_kernel<<<B_ * HP_ * 2, 256, 0, stream>>>(x, F);
    gemm_kernel<<<512, 256, 0, stream>>>(F, Wp, P);
    reduce_kernel<<<1024, 256, 0, stream>>>((const half8*)P, (float4*)out);
}

// Round 7
// 118.252 us; speedup vs baseline: 1.4354x; 1.0139x over previous
//
#include <hip/hip_runtime.h>
#include <hip/hip_bf16.h>

// Problem constants
#define B_      4
#define C_IN    64
#define H_      64
#define W_      64
#define OUT_CH  128
#define HP_     66          // padded height/width (halo = features(0))
#define CF      576         // K per tap: 9 features * 64 channels, cf = j*64 + c
#define WP_BYTES  (9 * OUT_CH * CF * 2)          // 1,327,104
#define F_BYTES   (B_ * HP_ * HP_ * CF * 2)      // 20,072,448
#define P_OFFSET  (WP_BYTES + F_BYTES)           // 21,399,552 (16B aligned)
#define NSPLIT  6
// partials: 6 groups x 524288 half4 x 8 B = 25,165,824 B (ws end ~46.6 MB)

typedef __bf16 bf16x8 __attribute__((ext_vector_type(8)));
typedef float  f32x4  __attribute__((ext_vector_type(4)));
typedef _Float16 half4 __attribute__((ext_vector_type(4)));

// silu + cubic B-spline bases (Cox-de Boor) — identical semantics to r1-r6 (passed).
__device__ __forceinline__ void compute_features(float x, float f[9]) {
    f[0] = x / (1.0f + __expf(-x));
    float g[12];
#pragma unroll
    for (int i = 0; i < 12; ++i) g[i] = (float)(i - 3) * 0.4f - 1.0f;
    float bb[11];
#pragma unroll
    for (int i = 0; i < 11; ++i) bb[i] = (x >= g[i] && x < g[i + 1]) ? 1.0f : 0.0f;
#pragma unroll
    for (int i = 0; i < 10; ++i)
        bb[i] = (x - g[i]) * (1.0f / (g[i + 1] - g[i])) * bb[i]
              + (g[i + 2] - x) * (1.0f / (g[i + 2] - g[i + 1])) * bb[i + 1];
#pragma unroll
    for (int i = 0; i < 9; ++i)
        bb[i] = (x - g[i]) * (1.0f / (g[i + 2] - g[i])) * bb[i]
              + (g[i + 3] - x) * (1.0f / (g[i + 3] - g[i + 1])) * bb[i + 1];
#pragma unroll
    for (int i = 0; i < 8; ++i)
        bb[i] = (x - g[i]) * (1.0f / (g[i + 3] - g[i])) * bb[i]
              + (g[i + 4] - x) * (1.0f / (g[i + 4] - g[i + 1])) * bb[i + 1];
#pragma unroll
    for (int i = 0; i < 8; ++i) f[1 + i] = bb[i];
}

// Kernel 1: pack merged weights -> bf16, Wp[(tap*128 + o)*576 + j*64 + c].
__global__ __launch_bounds__(256) void pack_kernel(
        const float* __restrict__ bw, const float* __restrict__ sw,
        const float* __restrict__ sc, __hip_bfloat16* __restrict__ Wp) {
    int idx = blockIdx.x * 256 + threadIdx.x;          // 0 .. 663551
    if (idx < 589824) {                                 // spline: idx = o*4608 + d*8 + j
        int o = idx / 4608;
        int r = idx - o * 4608;
        int d = r >> 3;
        int j = r & 7;
        int tap = d % 9;
        int c   = d / 9;
        float v = sw[idx] * sc[o * 576 + d];
        Wp[(tap * OUT_CH + o) * CF + (j + 1) * 64 + c] = __float2bfloat16(v);
    } else {                                            // base: k = o*576 + d
        int k = idx - 589824;
        int o = k / 576;
        int d = k - o * 576;
        int tap = d % 9;
        int c   = d / 9;
        Wp[(tap * OUT_CH + o) * CF + c] = __float2bfloat16(bw[k]);
    }
}

// Kernel 2: per-pixel features with halo. F[((b*66+hp)*66+wp)*576 + j*64 + c]
// 528 blocks (2 per image row, half the wp range each) ~ 2 blocks/CU.
__global__ __launch_bounds__(256) void feat_kernel(
        const float* __restrict__ x, __hip_bfloat16* __restrict__ F) {
    __shared__ float xs[64][65];
    int blk  = blockIdx.x;
    int half = blk & 1;
    int hp   = (blk >> 1) % HP_;
    int b    = blk / (2 * HP_);
    int h    = hp - 1;
    int tid  = threadIdx.x;

    float f0[9];
    compute_features(0.0f, f0);

    bool interior_row = (h >= 0) && (h < H_);
    if (interior_row) {
        int wl  = tid & 63;
        int c16 = tid >> 6;
#pragma unroll
        for (int i = 0; i < 16; ++i) {
            int c = c16 * 16 + i;
            xs[c][wl] = x[((b * C_IN + c) * H_ + h) * W_ + wl];
        }
    }
    __syncthreads();

    int c  = tid & 63;
    int wg = tid >> 6;
    __hip_bfloat16* Frow = F + (size_t)((b * HP_ + hp) * HP_) * CF;

    if (!interior_row) {
        int wp0 = half * 33;
        for (int wp = wp0 + wg; wp < wp0 + 33; wp += 4) {
            __hip_bfloat16* dst = Frow + (size_t)wp * CF + c;
#pragma unroll
            for (int j = 0; j < 9; ++j) dst[j * 64] = __float2bfloat16(f0[j]);
        }
        return;
    }
    if (half == 0 && wg == 0) {
        __hip_bfloat16* dst = Frow + c;                      // wp = 0
#pragma unroll
        for (int j = 0; j < 9; ++j) dst[j * 64] = __float2bfloat16(f0[j]);
    }
    if (half == 1 && wg == 3) {
        __hip_bfloat16* dst = Frow + (size_t)65 * CF + c;    // wp = 65
#pragma unroll
        for (int j = 0; j < 9; ++j) dst[j * 64] = __float2bfloat16(f0[j]);
    }
    int w2base = half * 32;
    for (int w2 = w2base + wg; w2 < w2base + 32; w2 += 4) {
        float xv = xs[c][w2];
        float f[9];
        compute_features(xv, f);
        __hip_bfloat16* dst = Frow + (size_t)(w2 + 1) * CF + c;
#pragma unroll
        for (int j = 0; j < 9; ++j) dst[j * 64] = __float2bfloat16(f[j]);
    }
}

// Kernel 3: implicit-GEMM, m97 recipe at 3 blocks/CU with 64x128 wave tile.
// Grid 768 = 6 k-groups x 128 pixel tiles (2 output rows) = exactly 3 blocks/CU,
// zero tail. Block = 128 threads = 2 waves; wave = 64 o x 128 px (4 mt x 8 nt of
// 16x16x32 bf16, 128-AGPR acc) -> 64 MFMA per barrier per wave, 384 LDS-B/MFMA.
// LDS 32 KB single-buffered (As 128px x 64k, Bs 128o x 64k, XOR-swizzled 16B
// granules), staged via global_load_lds dwordx4 (lane-contiguous). Sync is the
// plain 2-barrier m97 structure; latency hiding comes from the 3 co-resident
// blocks (m114 cross-block overlap), not source-level pipelining (m131/m135).
__global__ __launch_bounds__(128, 2) void gemm_kernel(
        const __hip_bfloat16* __restrict__ Fb, const __hip_bfloat16* __restrict__ Wpb,
        half4* __restrict__ P) {
    __shared__ __align__(16) ushort As[1024 * 8];   // 16 KB features
    __shared__ __align__(16) ushort Bs[1024 * 8];   // 16 KB weights

    const ushort* F  = (const ushort*)Fb;
    const ushort* Wp = (const ushort*)Wpb;

    int tid  = threadIdx.x;
    int lane = tid & 63;
    int w    = tid >> 6;             // 0..1 = out_ch half
    int l15  = lane & 15;
    int lq   = lane >> 4;

    int blk = blockIdx.x;
    int g   = blk >> 7;              // k-group 0..5
    int t   = blk & 127;
    int b   = t >> 5;
    int ho0 = (t & 31) << 1;         // 2 output rows
    int c0  = (g < 3) ? g * 14 : 42 + (g - 3) * 13;   // 81 chunks (tap*9+kc)
    int n   = (g < 3) ? 14 : 13;

    f32x4 acc[4][8];
#pragma unroll
    for (int i = 0; i < 4; ++i)
#pragma unroll
        for (int j = 0; j < 8; ++j) acc[i][j] = (f32x4){0.f, 0.f, 0.f, 0.f};

    for (int ii = 0; ii < n; ++ii) {
        int ch  = c0 + ii;
        int tap = ch / 9;
        int kc  = ch - tap * 9;
        int kh  = tap / 3;
        int kw  = tap - kh * 3;
        __syncthreads();             // readers of previous chunk done (WAR)
        // ---- stage A (128 px x 64 k) and B (128 o x 64 k): 8 rounds each ----
#pragma unroll
        for (int i = 0; i < 8; ++i) {
            int idx = i * 128 + tid;            // granule id 0..1023
            int row = idx >> 3;                 // pixel / o
            int c8  = (idx & 7) ^ (row & 7);    // XOR swizzle
            int hp  = ho0 + (row >> 6) + kh;
            int wp  = (row & 63) + kw;
            const ushort* srcA = F + (size_t)((b * HP_ + hp) * HP_ + wp) * CF
                                   + kc * 64 + c8 * 8;
            __builtin_amdgcn_global_load_lds(
                (const __attribute__((address_space(1))) unsigned int*)srcA,
                (__attribute__((address_space(3))) unsigned int*)&As[idx * 8],
                16, 0, 0);
            const ushort* srcB = Wp + (size_t)(tap * OUT_CH + row) * CF
                                    + kc * 64 + c8 * 8;
            __builtin_amdgcn_global_load_lds(
                (const __attribute__((address_space(1))) unsigned int*)srcB,
                (__attribute__((address_space(3))) unsigned int*)&Bs[idx * 8],
                16, 0, 0);
        }
        __syncthreads();             // data landed (compiler drains vmcnt here)
#pragma unroll
        for (int ks = 0; ks < 2; ++ks) {
            bf16x8 wf[4], af[8];
#pragma unroll
            for (int mt = 0; mt < 4; ++mt) {
                int o  = w * 64 + mt * 16 + l15;
                int sl = o * 8 + ((ks * 4 + lq) ^ (o & 7));
                wf[mt] = *(const bf16x8*)&Bs[sl * 8];
            }
#pragma unroll
            for (int nt = 0; nt < 8; ++nt) {
                int p  = nt * 16 + l15;
                int sl = p * 8 + ((ks * 4 + lq) ^ (p & 7));
                af[nt] = *(const bf16x8*)&As[sl * 8];
            }
#pragma unroll
            for (int mt = 0; mt < 4; ++mt)
#pragma unroll
                for (int nt = 0; nt < 8; ++nt)
                    acc[mt][nt] = __builtin_amdgcn_mfma_f32_16x16x32_bf16(
                        wf[mt], af[nt], acc[mt][nt], 0, 0, 0);
        }
    }

    // epilogue: coalesced fp16 partials, 512 B per store-row.
    // P[blk*4096 + (w*32 + mt*8 + nt)*64 + lane]
    half4* Pp = P + (size_t)blk * 4096 + (size_t)w * 2048 + lane;
#pragma unroll
    for (int mt = 0; mt < 4; ++mt)
#pragma unroll
        for (int nt = 0; nt < 8; ++nt) {
            half4 h;
#pragma unroll
            for (int r = 0; r < 4; ++r) h[r] = (_Float16)acc[mt][nt][r];
            Pp[(mt * 8 + nt) * 64] = h;
        }
}

// Kernel 4: reduce 6 permuted fp16 partials -> fp32 out (decodes the layout).
__global__ __launch_bounds__(256) void reduce_kernel(
        const half4* __restrict__ P, float* __restrict__ out) {
    const int GS = 524288;                    // half4 per k-group (128 tiles * 4096)
    int i = blockIdx.x * 256 + threadIdx.x;   // 0..524287
    float s[4] = {0.f, 0.f, 0.f, 0.f};
#pragma unroll
    for (int g = 0; g < NSPLIT; ++g) {
        half4 v = P[(size_t)g * GS + i];
#pragma unroll
        for (int r = 0; r < 4; ++r) s[r] += (float)v[r];
    }
    int lane = i & 63;
    int fr   = (i >> 6) & 31;
    int w    = (i >> 11) & 1;
    int t    = i >> 12;                       // 0..127
    int l15 = lane & 15, lq = lane >> 4;
    int mt = fr >> 3, nt = fr & 7;
    int o  = w * 64 + mt * 16 + lq * 4;
    int pp = nt * 16 + l15;                   // 0..127
    int b  = t >> 5;
    int ho = ((t & 31) << 1) + (pp >> 6);
    int wo = pp & 63;
    float* dst = out + ((size_t)(b * OUT_CH + o) << 12) + (ho << 6) + wo;
#pragma unroll
    for (int r = 0; r < 4; ++r)
        dst[(size_t)r << 12] = s[r];
}

extern "C" void kernel_launch(void* const* d_in, const int* in_sizes, int n_in,
                              void* d_out, int out_size, void* d_ws, size_t ws_size,
                              hipStream_t stream) {
    const float* x  = (const float*)d_in[0];   // (4,64,64,64)
    const float* bw = (const float*)d_in[1];   // (128,576)
    const float* sw = (const float*)d_in[2];   // (128,576,8)
    const float* sc = (const float*)d_in[3];   // (128,576)
    float* out = (float*)d_out;                // (4,128,64,64) fp32

    __hip_bfloat16* Wp = (__hip_bfloat16*)d_ws;
    __hip_bfloat16* F  = (__hip_bfloat16*)((char*)d_ws + WP_BYTES);
    half4*          P  = (half4*)((char*)d_ws + P_OFFSET);

    pack_kernel<<<2592, 256, 0, stream>>>(bw, sw, sc, Wp);
    feat_kernel<<<B_ * HP_ * 2, 256, 0, stream>>>(x, F);
    gemm_kernel<<<768, 128, 0, stream>>>(F, Wp, P);
    reduce_kernel<<<2048, 256, 0, stream>>>(P, out);
}